// Round 13
// baseline (86537.805 us; speedup 1.0000x reference)
//
#include <hip/hip_runtime.h>

// Echo-state network recurrence on MI355X (gfx950).
// Round-13: r12 transport (single-XCD team, 4-byte fused value24+tag8
// elements, plain publish, sc1 poll — 49.8ms) + BATCH-GRANULAR poll/consume.
// The spin now tracks validity per 1KB batch (one dwordx4/lane each):
// re-issue only still-invalid batches, then FMA the newly-valid ones WHILE
// the re-issued loads fly. Cuts futile-round traffic (the 512KB/round L2
// wall shrinks as batches complete) and hides ~3/4 of the 256-cyc FMA under
// load flight. Per-lane state; exec-masked re-issue preserves valid lanes'
// registers. Same numerics (0.125 absmax), same protocol safety.

#define HH    1024
#define TT    50000
#define WASH  200
#define NROLE 128   // role w owns rows [8w, 8w+8)
#define NBLK  2048
#define NT    64
#define SPIN_CAP (1u << 20)

typedef unsigned int u32;
typedef u32 u32x4 __attribute__((ext_vector_type(4)));
typedef float f32x4 __attribute__((ext_vector_type(4)));

__device__ __forceinline__ float fast_tanh(float x) {
  // tanh(x) = 1 - 2/(exp2(2x*log2e)+1); safe at +/-inf.
  float e = __builtin_amdgcn_exp2f(x * 2.8853900817779268f);
  return fmaf(-2.0f, __builtin_amdgcn_rcpf(e + 1.0f), 1.0f);
}

template <int CTRL>
__device__ __forceinline__ float dpp_movf(float x) {
  return __int_as_float(__builtin_amdgcn_update_dpp(
      0, __float_as_int(x), CTRL, 0xF, 0xF, true));
}
__device__ __forceinline__ float swz_xor16(float x) {
  return __int_as_float(__builtin_amdgcn_ds_swizzle(__float_as_int(x), 0x401F));
}

#define YREDUCE()                                                         \
  { y += __shfl_xor(y, 32);                                               \
    y += swz_xor16(y);                                                    \
    y += dpp_movf<0x128>(y);   /* row_ror:8   */                          \
    y += dpp_movf<0x141>(y);   /* half mirror */                          \
    y += dpp_movf<0x1B>(y);    /* quad reverse*/                          \
    y += dpp_movf<0xB1>(y); }  /* quad xor1   */

// batch k: lane l covers packed cols {256k+4l .. 256k+4l+3}
#define ISSUE0 asm volatile("global_load_dwordx4 %0, %1, off sc1"             : "=v"(p0) : "v"(b))
#define ISSUE1 asm volatile("global_load_dwordx4 %0, %1, off offset:1024 sc1" : "=v"(p1) : "v"(b))
#define ISSUE2 asm volatile("global_load_dwordx4 %0, %1, off offset:2048 sc1" : "=v"(p2) : "v"(b))
#define ISSUE3 asm volatile("global_load_dwordx4 %0, %1, off offset:3072 sc1" : "=v"(p3) : "v"(b))
#define WAITP                                                             \
  asm volatile("s_waitcnt vmcnt(0)"                                       \
               : "+v"(p0), "+v"(p1), "+v"(p2), "+v"(p3))

#define OKB(p) ((((p.x ^ want) | (p.y ^ want) | (p.z ^ want) | (p.w ^ want)) & 0xFFu) == 0u)

#define UNPACK(p, base)                                                   \
  { xv[base+0] = __uint_as_float(p.x & 0xFFFFFF00u);                      \
    xv[base+1] = __uint_as_float(p.y & 0xFFFFFF00u);                      \
    xv[base+2] = __uint_as_float(p.z & 0xFFFFFF00u);                      \
    xv[base+3] = __uint_as_float(p.w & 0xFFFFFF00u); }

#define FMA_B(k)                                                          \
  _Pragma("unroll")                                                       \
  for (int c = 0; c < 4; ++c)                                             \
    _Pragma("unroll")                                                     \
    for (int row = 0; row < 8; ++row)                                     \
      acc[row] = fmaf(wr[row][4*(k)+c], xv[4*(k)+c], acc[row]);

__global__ __launch_bounds__(NT, 2) void esn_kernel(
    const float* __restrict__ u,
    const float* __restrict__ w_in,
    const float* __restrict__ w_res,
    const float* __restrict__ w_out,
    const int*   __restrict__ mask,
    float*       __restrict__ out,
    char*        __restrict__ ws)
{
  const int l = threadIdx.x;

  // --- team formation: XCD 0 only, first 128 claimants persist (r9-proven) ---
  u32 xcc;
  asm("s_getreg_b32 %0, hwreg(HW_REG_XCC_ID)" : "=s"(xcc));
  if (xcc != 0) return;
  int slot = 0;
  if (l == 0) slot = atomicAdd((int*)ws, 1);   // ws[0..63] zeroed each launch
  slot = __shfl(slot, 0);
  if (slot >= NROLE) return;
  const int w = slot;                          // role: rows [8w, 8w+8)

  u32* xb0 = (u32*)(ws + 4096);        // parity-0 packed buffer (4 KB)
  u32* xb1 = xb0 + HH;                 // parity-1 packed buffer (4 KB)

  __shared__ float lds_c[HH];
  for (int h = l; h < HH; h += NT) lds_c[mask[h]] = w_out[h];
  __syncthreads();

  // weights: 8 rows x 16 cols per lane; j=4k+c <-> col 256k+4l+c
  float wr[8][16];
#pragma unroll
  for (int row = 0; row < 8; ++row) {
    const float* wp = w_res + (size_t)(8 * w + row) * HH + 4 * l;
#pragma unroll
    for (int k = 0; k < 4; ++k) {
      f32x4 v = *(const f32x4*)(wp + 256 * k);
      wr[row][4*k+0] = v.x; wr[row][4*k+1] = v.y;
      wr[row][4*k+2] = v.z; wr[row][4*k+3] = v.w;
    }
  }
  const float win = w_in[8 * w + (l >> 3)];    // lane (l&7)==0 stores row 8w+(l>>3)

  float cr[16];                                // readout coeffs, same col map
#pragma unroll
  for (int k = 0; k < 4; ++k) {
    f32x4 v = *(const f32x4*)(lds_c + 256 * k + 4 * l);
    cr[4*k+0] = v.x; cr[4*k+1] = v.y; cr[4*k+2] = v.z; cr[4*k+3] = v.w;
  }

  const u32* pA0 = xb0 + 4 * l;
  const u32* pA1 = xb1 + 4 * l;
  const int drow = 8 * w + (l >> 3);
  u32* d0 = xb0 + drow;
  u32* d1 = xb1 + drow;

  u32x4 p0, p1, p2, p3;
  const int lb32 = l & 32, lb16 = l & 16, lb8 = l & 8;
  int dead = 0;

  for (int t = 0; t < TT; ++t) {
    const int pa = t & 1;
    const float u_t = u[t];
    float acc[8];
#pragma unroll
    for (int i = 0; i < 8; ++i) acc[i] = 0.f;
    float xv[16];
    const bool doRead = ((t & 127) == w) && (t > 0);

    if (t > 0 && !dead) {
      const u32* b = pa ? pA0 : pA1;    // source = buf[(t-1)&1]
      const u32 want = (u32)t & 0xFFu;  // generation of x_{t-1}
      u32 vm = 0, guard = 0;
      ISSUE0; ISSUE1; ISSUE2; ISSUE3;
      for (;;) {
        WAITP;
        // which batches just became valid (per lane)?
        u32 nw = 0;
        if (!(vm & 1u) && OKB(p0)) nw |= 1u;
        if (!(vm & 2u) && OKB(p1)) nw |= 2u;
        if (!(vm & 4u) && OKB(p2)) nw |= 4u;
        if (!(vm & 8u) && OKB(p3)) nw |= 8u;
        vm |= nw;
        if (vm != 0xFu) {
          // re-issue still-invalid batches FIRST (their flight overlaps the
          // FMAs below); exec-masked loads don't touch valid lanes' regs
          if (!(vm & 1u)) ISSUE0;
          if (!(vm & 2u)) ISSUE1;
          if (!(vm & 4u)) ISSUE2;
          if (!(vm & 8u)) ISSUE3;
        }
        // consume newly-valid batches while (possible) re-polls fly
        if (nw & 1u) { UNPACK(p0, 0);  FMA_B(0); }
        if (nw & 2u) { UNPACK(p1, 4);  FMA_B(1); }
        if (nw & 4u) { UNPACK(p2, 8);  FMA_B(2); }
        if (nw & 8u) { UNPACK(p3, 12); FMA_B(3); }
        if (vm == 0xFu) break;
        if (++guard > SPIN_CAP) { dead = 1; break; }
      }
    }

    // fold 64 lanes x 8 accs -> row (l>>3) sum on lanes with (l&7)==0
    float t0 = (lb32 ? acc[4] : acc[0]) + __shfl_xor(lb32 ? acc[0] : acc[4], 32);
    float t1 = (lb32 ? acc[5] : acc[1]) + __shfl_xor(lb32 ? acc[1] : acc[5], 32);
    float t2 = (lb32 ? acc[6] : acc[2]) + __shfl_xor(lb32 ? acc[2] : acc[6], 32);
    float t3 = (lb32 ? acc[7] : acc[3]) + __shfl_xor(lb32 ? acc[3] : acc[7], 32);
    float s0 = (lb16 ? t2 : t0) + swz_xor16(lb16 ? t0 : t2);
    float s1 = (lb16 ? t3 : t1) + swz_xor16(lb16 ? t1 : t3);
    float r0 = (lb8 ? s1 : s0) + dpp_movf<0x128>(lb8 ? s0 : s1);
    r0 += dpp_movf<0x141>(r0);
    r0 += dpp_movf<0x1B>(r0);
    r0 += dpp_movf<0xB1>(r0);

    float x_new = fast_tanh(fmaf(win, u_t, r0));
    // pack: RN-round mantissa to 15 bits, fuse generation tag (t+1)&0xFF
    u32 packed = ((__float_as_uint(x_new) + 0x80u) & 0xFFFFFF00u)
               | ((u32)(t + 1) & 0xFFu);
    if ((l & 7) == 0) {
      u32* dst = pa ? d1 : d0;          // x_t -> buf[t&1]
      // PLAIN store: write-through L1 -> dirty in XCD0's shared L2 (r9-proven)
      asm volatile("global_store_dword %0, %1, off" :: "v"(dst), "v"(packed));
    }

    // readout y_{t-1} from this step's unpacked values (off critical path)
    if (doRead) {
      float y = 0.f;
#pragma unroll
      for (int j = 0; j < 16; ++j) y = fmaf(cr[j], xv[j], y);
      YREDUCE();
      if (l == 0 && t - 1 >= WASH) out[t - 1 - WASH] = y;
    }
  }

  // final readout: x_{TT-1} published but never consumed in-loop (role 0)
  if (w == 0) {
    const u32 want = (u32)TT & 0xFFu;   // x_{TT-1} lives in buf[(TT-1)&1]=buf[1]
    const u32* b = pA1;
    u32 guard = 0;
    for (;;) {
      ISSUE0; ISSUE1; ISSUE2; ISSUE3;
      WAITP;
      if (OKB(p0) && OKB(p1) && OKB(p2) && OKB(p3)) break;
      if (++guard > SPIN_CAP) break;
    }
    float xv[16];
    UNPACK(p0, 0); UNPACK(p1, 4); UNPACK(p2, 8); UNPACK(p3, 12);
    float y = 0.f;
#pragma unroll
    for (int j = 0; j < 16; ++j) y = fmaf(cr[j], xv[j], y);
    YREDUCE();
    if (l == 0) out[TT - 1 - WASH] = y;
  }
}

extern "C" void kernel_launch(void* const* d_in, const int* in_sizes, int n_in,
                              void* d_out, int out_size, void* d_ws, size_t ws_size,
                              hipStream_t stream) {
  const float* u     = (const float*)d_in[0];
  const float* w_in  = (const float*)d_in[1];
  const float* w_res = (const float*)d_in[2];
  const float* w_out = (const float*)d_in[3];
  const int*   mask  = (const int*)d_in[4];
  float* out = (float*)d_out;

  // zero the role-claim counter; packed buffers rely on 0xAA poison
  // (tag byte 0xAA only ever compared against want in {1,2})
  hipMemsetAsync(d_ws, 0, 64, stream);

  esn_kernel<<<NBLK, NT, 0, stream>>>(u, w_in, w_res, w_out, mask, out,
                                      (char*)d_ws);
}

// Round 14
// 50292.581 us; speedup vs baseline: 1.7207x; 1.7207x over previous
//
#include <hip/hip_runtime.h>

// Echo-state network recurrence on MI355X (gfx950).
// Round-14: EXACT r12 kernel (single-XCD team, 4-byte fused value24+tag8
// elements, plain publish, sc1 poll — 49.8ms) + s_sleep-paced first sample.
// r13 post-mortem: per-lane divergent spin doubled round cost — detect loop
// must stay short & wave-uniform. r12 residual analysis: waves start polling
// ~250cyc before data can be ready (publish+L2 visibility ~300cyc), so round
// 1 is almost always futile — pure contention. Fix: s_sleep 2 (~128cyc)
// before the FIRST poll issue each step; first sample lands at readiness,
// futile-round traffic (~half of all poll load) disappears, RT and producer
// stagger compress. Laggard pays +128cyc worst case; majority saves ~250+.

#define HH    1024
#define TT    50000
#define WASH  200
#define NROLE 128   // role w owns rows [8w, 8w+8)
#define NBLK  2048
#define NT    64
#define SPIN_CAP (1u << 20)

typedef unsigned int u32;
typedef u32 u32x4 __attribute__((ext_vector_type(4)));
typedef float f32x4 __attribute__((ext_vector_type(4)));

__device__ __forceinline__ float fast_tanh(float x) {
  // tanh(x) = 1 - 2/(exp2(2x*log2e)+1); safe at +/-inf.
  float e = __builtin_amdgcn_exp2f(x * 2.8853900817779268f);
  return fmaf(-2.0f, __builtin_amdgcn_rcpf(e + 1.0f), 1.0f);
}

template <int CTRL>
__device__ __forceinline__ float dpp_movf(float x) {
  return __int_as_float(__builtin_amdgcn_update_dpp(
      0, __float_as_int(x), CTRL, 0xF, 0xF, true));
}
__device__ __forceinline__ float swz_xor16(float x) {
  return __int_as_float(__builtin_amdgcn_ds_swizzle(__float_as_int(x), 0x401F));
}

#define YREDUCE()                                                         \
  { y += __shfl_xor(y, 32);                                               \
    y += swz_xor16(y);                                                    \
    y += dpp_movf<0x128>(y);   /* row_ror:8   */                          \
    y += dpp_movf<0x141>(y);   /* half mirror */                          \
    y += dpp_movf<0x1B>(y);    /* quad reverse*/                          \
    y += dpp_movf<0xB1>(y); }  /* quad xor1   */

// 4 batched 16B poll loads covering all 1024 packed elements.
// Load k, lane l -> cols {256k+4l .. 256k+4l+3}.
#define POLL_ISSUE(b)                                                                 \
  asm volatile("global_load_dwordx4 %0, %1, off sc1"             : "=v"(p0) : "v"(b)); \
  asm volatile("global_load_dwordx4 %0, %1, off offset:1024 sc1" : "=v"(p1) : "v"(b)); \
  asm volatile("global_load_dwordx4 %0, %1, off offset:2048 sc1" : "=v"(p2) : "v"(b)); \
  asm volatile("global_load_dwordx4 %0, %1, off offset:3072 sc1" : "=v"(p3) : "v"(b))

#define POLL_WAIT0()                                                      \
  asm volatile("s_waitcnt vmcnt(0)"                                       \
               : "+v"(p0), "+v"(p1), "+v"(p2), "+v"(p3))

#define TAGBAD(p) ((p.x ^ want) | (p.y ^ want) | (p.z ^ want) | (p.w ^ want))
#define TAGBAD_ALL ((TAGBAD(p0) | TAGBAD(p1) | TAGBAD(p2) | TAGBAD(p3)) & 0xFFu)

#define UNPACK(p, base)                                                   \
  { xv[base+0] = __uint_as_float(p.x & 0xFFFFFF00u);                      \
    xv[base+1] = __uint_as_float(p.y & 0xFFFFFF00u);                      \
    xv[base+2] = __uint_as_float(p.z & 0xFFFFFF00u);                      \
    xv[base+3] = __uint_as_float(p.w & 0xFFFFFF00u); }

__global__ __launch_bounds__(NT, 2) void esn_kernel(
    const float* __restrict__ u,
    const float* __restrict__ w_in,
    const float* __restrict__ w_res,
    const float* __restrict__ w_out,
    const int*   __restrict__ mask,
    float*       __restrict__ out,
    char*        __restrict__ ws)
{
  const int l = threadIdx.x;

  // --- team formation: XCD 0 only, first 128 claimants persist (r9-proven) ---
  u32 xcc;
  asm("s_getreg_b32 %0, hwreg(HW_REG_XCC_ID)" : "=s"(xcc));
  if (xcc != 0) return;
  int slot = 0;
  if (l == 0) slot = atomicAdd((int*)ws, 1);   // ws[0..63] zeroed each launch
  slot = __shfl(slot, 0);
  if (slot >= NROLE) return;
  const int w = slot;                          // role: rows [8w, 8w+8)

  u32* xb0 = (u32*)(ws + 4096);        // parity-0 packed buffer (4 KB)
  u32* xb1 = xb0 + HH;                 // parity-1 packed buffer (4 KB)

  __shared__ float lds_c[HH];
  for (int h = l; h < HH; h += NT) lds_c[mask[h]] = w_out[h];
  __syncthreads();

  // weights: 8 rows x 16 cols per lane; j=4k+c <-> col 256k+4l+c
  float wr[8][16];
#pragma unroll
  for (int row = 0; row < 8; ++row) {
    const float* wp = w_res + (size_t)(8 * w + row) * HH + 4 * l;
#pragma unroll
    for (int k = 0; k < 4; ++k) {
      f32x4 v = *(const f32x4*)(wp + 256 * k);
      wr[row][4*k+0] = v.x; wr[row][4*k+1] = v.y;
      wr[row][4*k+2] = v.z; wr[row][4*k+3] = v.w;
    }
  }
  const float win = w_in[8 * w + (l >> 3)];    // lane (l&7)==0 stores row 8w+(l>>3)

  float cr[16];                                // readout coeffs, same col map
#pragma unroll
  for (int k = 0; k < 4; ++k) {
    f32x4 v = *(const f32x4*)(lds_c + 256 * k + 4 * l);
    cr[4*k+0] = v.x; cr[4*k+1] = v.y; cr[4*k+2] = v.z; cr[4*k+3] = v.w;
  }

  const u32* pA0 = xb0 + 4 * l;
  const u32* pA1 = xb1 + 4 * l;
  const int drow = 8 * w + (l >> 3);
  u32* d0 = xb0 + drow;
  u32* d1 = xb1 + drow;

  u32x4 p0, p1, p2, p3;
  const int lb32 = l & 32, lb16 = l & 16, lb8 = l & 8;
  int dead = 0;

  for (int t = 0; t < TT; ++t) {
    const int pa = t & 1;
    const float u_t = u[t];
    float acc[8];
#pragma unroll
    for (int i = 0; i < 8; ++i) acc[i] = 0.f;
    float xv[16];
    const bool doRead = ((t & 127) == w) && (t > 0);

    if (t > 0 && !dead) {
      const u32* b = pa ? pA0 : pA1;    // source = buf[(t-1)&1]
      const u32 want = (u32)t & 0xFFu;  // generation of x_{t-1}
      u32 guard = 0;
      // pace: data can't be ready before publish+visibility (~300cyc);
      // sleeping ~128cyc turns the guaranteed-futile first round into idle
      asm volatile("s_sleep 2");
      for (;;) {
        POLL_ISSUE(b);
        POLL_WAIT0();
        if (!TAGBAD_ALL) break;
        if (++guard > SPIN_CAP) { dead = 1; break; }
      }
      UNPACK(p0, 0); UNPACK(p1, 4); UNPACK(p2, 8); UNPACK(p3, 12);
#pragma unroll
      for (int j = 0; j < 16; ++j)
#pragma unroll
        for (int row = 0; row < 8; ++row)
          acc[row] = fmaf(wr[row][j], xv[j], acc[row]);
    }

    // fold 64 lanes x 8 accs -> row (l>>3) sum on lanes with (l&7)==0
    float t0 = (lb32 ? acc[4] : acc[0]) + __shfl_xor(lb32 ? acc[0] : acc[4], 32);
    float t1 = (lb32 ? acc[5] : acc[1]) + __shfl_xor(lb32 ? acc[1] : acc[5], 32);
    float t2 = (lb32 ? acc[6] : acc[2]) + __shfl_xor(lb32 ? acc[2] : acc[6], 32);
    float t3 = (lb32 ? acc[7] : acc[3]) + __shfl_xor(lb32 ? acc[3] : acc[7], 32);
    float s0 = (lb16 ? t2 : t0) + swz_xor16(lb16 ? t0 : t2);
    float s1 = (lb16 ? t3 : t1) + swz_xor16(lb16 ? t1 : t3);
    float r0 = (lb8 ? s1 : s0) + dpp_movf<0x128>(lb8 ? s0 : s1);
    r0 += dpp_movf<0x141>(r0);
    r0 += dpp_movf<0x1B>(r0);
    r0 += dpp_movf<0xB1>(r0);

    float x_new = fast_tanh(fmaf(win, u_t, r0));
    // pack: RN-round mantissa to 15 bits, fuse generation tag (t+1)&0xFF
    u32 packed = ((__float_as_uint(x_new) + 0x80u) & 0xFFFFFF00u)
               | ((u32)(t + 1) & 0xFFu);
    if ((l & 7) == 0) {
      u32* dst = pa ? d1 : d0;          // x_t -> buf[t&1]
      // PLAIN store: write-through L1 -> dirty in XCD0's shared L2 (r9-proven)
      asm volatile("global_store_dword %0, %1, off" :: "v"(dst), "v"(packed));
    }

    // readout y_{t-1} from this step's unpacked values (off critical path)
    if (doRead) {
      float y = 0.f;
#pragma unroll
      for (int j = 0; j < 16; ++j) y = fmaf(cr[j], xv[j], y);
      YREDUCE();
      if (l == 0 && t - 1 >= WASH) out[t - 1 - WASH] = y;
    }
  }

  // final readout: x_{TT-1} published but never consumed in-loop (role 0)
  if (w == 0) {
    const u32 want = (u32)TT & 0xFFu;   // x_{TT-1} lives in buf[(TT-1)&1]=buf[1]
    u32 guard = 0;
    for (;;) {
      POLL_ISSUE(pA1);
      POLL_WAIT0();
      if (!TAGBAD_ALL) break;
      if (++guard > SPIN_CAP) break;
    }
    float xv[16];
    UNPACK(p0, 0); UNPACK(p1, 4); UNPACK(p2, 8); UNPACK(p3, 12);
    float y = 0.f;
#pragma unroll
    for (int j = 0; j < 16; ++j) y = fmaf(cr[j], xv[j], y);
    YREDUCE();
    if (l == 0) out[TT - 1 - WASH] = y;
  }
}

extern "C" void kernel_launch(void* const* d_in, const int* in_sizes, int n_in,
                              void* d_out, int out_size, void* d_ws, size_t ws_size,
                              hipStream_t stream) {
  const float* u     = (const float*)d_in[0];
  const float* w_in  = (const float*)d_in[1];
  const float* w_res = (const float*)d_in[2];
  const float* w_out = (const float*)d_in[3];
  const int*   mask  = (const int*)d_in[4];
  float* out = (float*)d_out;

  // zero the role-claim counter; packed buffers rely on 0xAA poison
  // (tag byte 0xAA only ever compared against want in {1,2})
  hipMemsetAsync(d_ws, 0, 64, stream);

  esn_kernel<<<NBLK, NT, 0, stream>>>(u, w_in, w_res, w_out, mask, out,
                                      (char*)d_ws);
}